// Round 8
// baseline (275.857 us; speedup 1.0000x reference)
//
#include <hip/hip_runtime.h>
#include <math.h>
#include <stdint.h>

#define D_DIM 128
#define SEQ 2048
#define NHEADS 32
#define BC 64
#define SCALE 0.08838834764831843f  // 1/sqrt(128)

typedef short bf16x8 __attribute__((ext_vector_type(8)));
typedef float f32x4 __attribute__((ext_vector_type(4)));

union Frag { uint32_t u[4]; bf16x8 v; unsigned short s[8]; };
union Pack8 { unsigned short s[8]; uint4 q; };

__device__ __forceinline__ uint32_t fbits(float x) { return __builtin_bit_cast(uint32_t, x); }
__device__ __forceinline__ float bbits(uint32_t u) { return __builtin_bit_cast(float, u); }
__device__ __forceinline__ unsigned short bf16_rne(float x) {
    uint32_t u = fbits(x);
    u += 0x7FFFu + ((u >> 16) & 1u);
    return (unsigned short)(u >> 16);
}
// hi = truncate-to-bf16(x) (exact residual), lo = bf16(x - hi). even->low16, odd->high16.
__device__ __forceinline__ void split2(float a, float b, uint32_t& hp, uint32_t& lp) {
    uint32_t ua = fbits(a) & 0xFFFF0000u, ub = fbits(b) & 0xFFFF0000u;
    float la = a - bbits(ua), lb = b - bbits(ub);
    hp = (ua >> 16) | ub;
    lp = (fbits(la) >> 16) | (fbits(lb) & 0xFFFF0000u);
}

// ---------------- fused attention: conversion + FA in one kernel ----------------
// R8 = R7 + balanced block pairing. Grid is 512 blocks = exactly 2/CU, both resident
// from t=0; the resident pair is (x, x+256). R7's map gave pair work 48-4*xi
// tile-units (48..20, 2.4x imbalance -> 21% occupancy, makespan set by xi=0 CUs).
// New map pairs (it, 15-it): work = 264 units for EVERY pair. h = x&31 unchanged
// (256 = 0 mod 32) so paired blocks still share their head's K/V in L2.
// Rest identical to R7: T14 issue-early/convert-late staging pipeline, pure-ds_write
// barrier window, exact alpha==1 skip, SCALE folded into Q, deferred per-lane l,
// interior-tile mask skip, 64KB LDS, launch_bounds(512,2) (NOT (512,4): R2 spills).
// 16x16x32 bf16 MFMA; layouts: A[m=lane&15][k=quad*8+j], B[k=quad*8+j][n=lane&15],
// C/D[row=quad*4+reg][col=lane&15].
// Khs[n*128 + ((kc8^(n&7))*8)]  (n=row 0..63, kc8=k-chunk-of-8 0..15), Kls same.
// Vhs[d*64 + ((cc^(d&7))*8) + j] = bf16_rne(V[c0+cc*8+j][d]).
__global__ __launch_bounds__(512, 2) void fa_fused(
    const float* __restrict__ q, const float* __restrict__ k,
    const float* __restrict__ v, float* __restrict__ out)
{
    __shared__ __align__(16) unsigned short Khs[64 * 128];   // 16KB
    __shared__ __align__(16) unsigned short Kls[64 * 128];   // 16KB
    __shared__ __align__(16) unsigned short Vhs[128 * 64];   // 16KB
    __shared__ __align__(16) unsigned short Pbs[128 * 64];   // 16KB -> 64KB total

    // balanced pairing: x<256 -> it=15..8 ; x>=256 -> it=0..7 ; pair (x,x+256)=(it,15-it)
    const int x  = blockIdx.x;
    const int xi = x >> 5;                              // 0..15
    const int it = (x < 256) ? (15 - xi) : (xi - 8);
    const int h  = x & 31;

    const int t    = (int)threadIdx.x;
    const int wb   = t >> 6;
    const int lane = t & 63;
    const int ln   = lane & 15;
    const int qd   = lane >> 4;

    const float* qh = q + (size_t)h * SEQ * D_DIM;
    const float* kh = k + (size_t)h * SEQ * D_DIM;
    const float* vh = v + (size_t)h * SEQ * D_DIM;
    float* out_o = out;
    float* out_m = out + (size_t)NHEADS * SEQ * D_DIM;
    float* out_l = out_m + (size_t)NHEADS * SEQ * 8;

    const int qrow0 = it * 128 + wb * 16;

    // per-thread K staging coordinates (over 2048 float4 chunks of the 64x128 tile)
    const int krow0 = t >> 5;          // +16 per itr
    const int kd4   = t & 31;
    // per-thread V staging coordinates (2 units: uu selects d-half within wave's cc)
    const int vcc   = wb;
    const int vd0   = lane;            // d = uu*64 + lane

    // Q fragments (exact hi/lo split of SCALE*q) in registers: 32 VGPRs
    Frag Qh[4], Ql[4];
    {
        const float* qp = qh + (size_t)(qrow0 + ln) * D_DIM;
        #pragma unroll
        for (int kc = 0; kc < 4; ++kc) {
            const int kb = kc * 32 + qd * 8;
            float e[8];
            *(float4*)(e)     = *(const float4*)(qp + kb);
            *(float4*)(e + 4) = *(const float4*)(qp + kb + 4);
            #pragma unroll
            for (int j = 0; j < 8; ++j) e[j] *= SCALE;   // fold score scaling into Q
            #pragma unroll
            for (int j = 0; j < 4; ++j)
                split2(e[2 * j], e[2 * j + 1], Qh[kc].u[j], Ql[kc].u[j]);
        }
    }

    // pipeline registers: raw (in-flight) and converted (ready-to-store) K/V
    float4 kreg[4];
    float  vraw[2][8];
    uint2  khi[4], klo[4];
    uint4  vcv[2];

    // ---- prologue: tile 0 raw loads ----
    #pragma unroll
    for (int itr = 0; itr < 4; ++itr)
        kreg[itr] = *(const float4*)(kh + (size_t)(itr * 16 + krow0) * D_DIM + kd4 * 4);
    #pragma unroll
    for (int uu = 0; uu < 2; ++uu) {
        const int d = uu * 64 + vd0;
        #pragma unroll
        for (int j = 0; j < 8; ++j)
            vraw[uu][j] = vh[(size_t)(vcc * 8 + j) * D_DIM + d];
    }
    // ---- prologue: tile 0 conversion ----
    #pragma unroll
    for (int itr = 0; itr < 4; ++itr) {
        uint32_t hp0, lp0, hp1, lp1;
        split2(kreg[itr].x, kreg[itr].y, hp0, lp0);
        split2(kreg[itr].z, kreg[itr].w, hp1, lp1);
        khi[itr] = make_uint2(hp0, hp1);
        klo[itr] = make_uint2(lp0, lp1);
    }
    #pragma unroll
    for (int uu = 0; uu < 2; ++uu) {
        Pack8 p8;
        #pragma unroll
        for (int j = 0; j < 8; ++j) p8.s[j] = bf16_rne(vraw[uu][j]);
        vcv[uu] = p8.q;
    }

    f32x4 accO[8];
    float m_r[4], l_r[4];   // l_r is a PER-LANE partial (alpha is row-uniform, so exact)
    #pragma unroll
    for (int nd = 0; nd < 8; ++nd) accO[nd] = (f32x4){0.f, 0.f, 0.f, 0.f};
    #pragma unroll
    for (int r = 0; r < 4; ++r) { m_r[r] = -INFINITY; l_r[r] = 0.f; }

    const int jt_end = 2 * it + 1;
    for (int jt = 0; jt <= jt_end; ++jt) {
        const int c0 = jt * BC;

        __syncthreads();  // all waves done reading LDS from previous tile

        // ---- staging window: pure ds_writes from converted regs ----
        #pragma unroll
        for (int itr = 0; itr < 4; ++itr) {
            const int row = itr * 16 + krow0;
            const int off = row * 128 + (((kd4 >> 1) ^ (row & 7)) * 8) + (kd4 & 1) * 4;
            *(uint2*)(Khs + off) = khi[itr];
            *(uint2*)(Kls + off) = klo[itr];
        }
        #pragma unroll
        for (int uu = 0; uu < 2; ++uu) {
            const int d = uu * 64 + vd0;
            *(uint4*)(Vhs + d * 64 + ((vcc ^ (d & 7)) * 8)) = vcv[uu];
        }

        __syncthreads();  // staging visible

        if (jt < jt_end) {  // issue next tile's raw loads (latency hides under compute)
            const int c0n = c0 + BC;
            const float* kp2 = kh + (size_t)c0n * D_DIM;
            #pragma unroll
            for (int itr = 0; itr < 4; ++itr)
                kreg[itr] = *(const float4*)(kp2 + (size_t)(itr * 16 + krow0) * D_DIM + kd4 * 4);
            #pragma unroll
            for (int uu = 0; uu < 2; ++uu) {
                const int d = uu * 64 + vd0;
                #pragma unroll
                for (int j = 0; j < 8; ++j)
                    vraw[uu][j] = vh[(size_t)(c0n + vcc * 8 + j) * D_DIM + d];
            }
        }

        if (c0 <= qrow0 + 15) {  // wave-uniform causal skip
            // ---- S = (scaled Q) K^T (split-3: hh + hl + lh), 48 MFMAs ----
            f32x4 accS[4];
            #pragma unroll
            for (int nt = 0; nt < 4; ++nt) accS[nt] = (f32x4){0.f, 0.f, 0.f, 0.f};
            #pragma unroll
            for (int kc = 0; kc < 4; ++kc) {
                #pragma unroll
                for (int nt = 0; nt < 4; ++nt) {
                    int n = nt * 16 + ln;
                    int off = n * 128 + (((kc * 4 + qd) ^ (n & 7)) * 8);
                    Frag Bh, Bl;
                    Bh.v = *(const bf16x8*)(Khs + off);
                    Bl.v = *(const bf16x8*)(Kls + off);
                    f32x4 c = accS[nt];
                    c = __builtin_amdgcn_mfma_f32_16x16x32_bf16(Qh[kc].v, Bh.v, c, 0, 0, 0);
                    c = __builtin_amdgcn_mfma_f32_16x16x32_bf16(Qh[kc].v, Bl.v, c, 0, 0, 0);
                    c = __builtin_amdgcn_mfma_f32_16x16x32_bf16(Ql[kc].v, Bh.v, c, 0, 0, 0);
                    accS[nt] = c;
                }
            }
            // ---- online softmax ----
            const bool needMask = (c0 + 63 > qrow0);  // interior tiles need no causal mask
            float mxr[4];
            #pragma unroll
            for (int r = 0; r < 4; ++r) {
                const int rowg = qrow0 + qd * 4 + r;
                float mx = -INFINITY;
                #pragma unroll
                for (int nt = 0; nt < 4; ++nt) {
                    float s = accS[nt][r];
                    if (needMask && (c0 + nt * 16 + ln > rowg)) s = -INFINITY;  // causal
                    accS[nt][r] = s;
                    mx = fmaxf(mx, s);
                }
                mxr[r] = mx;
            }
            #pragma unroll
            for (int r = 0; r < 4; ++r) {
                #pragma unroll
                for (int off = 1; off < 16; off <<= 1) mxr[r] = fmaxf(mxr[r], __shfl_xor(mxr[r], off));
            }
            // exact alpha==1 skip: if no row's max grew, rescale is multiply-by-1.0
            const bool grow = (mxr[0] > m_r[0]) | (mxr[1] > m_r[1]) |
                              (mxr[2] > m_r[2]) | (mxr[3] > m_r[3]);
            if (__any(grow)) {
                #pragma unroll
                for (int r = 0; r < 4; ++r) {
                    const float mnew = fmaxf(m_r[r], mxr[r]);
                    const float alpha = __expf(m_r[r] - mnew);  // first live tile: exp(-inf)=0
                    m_r[r] = mnew;
                    l_r[r] *= alpha;
                    #pragma unroll
                    for (int nd = 0; nd < 8; ++nd) accO[nd][r] *= alpha;
                }
            }
            // pass 2: exponentials, per-lane l partial, P -> LDS
            #pragma unroll
            for (int r = 0; r < 4; ++r) {
                float p[4];
                #pragma unroll
                for (int nt = 0; nt < 4; ++nt) p[nt] = __expf(accS[nt][r] - m_r[r]);
                l_r[r] += (p[0] + p[1]) + (p[2] + p[3]);    // per-lane partial
                const int R = wb * 16 + qd * 4 + r;  // intra-wave P region
                #pragma unroll
                for (int nt = 0; nt < 4; ++nt) {
                    int c = nt * 16 + ln;
                    Pbs[R * 64 + (((c >> 3) ^ (R & 7)) * 8) + (c & 7)] = bf16_rne(p[nt]);
                }
            }
            // ---- O += P V_hi, 16 MFMAs ----
            #pragma unroll
            for (int kc2 = 0; kc2 < 2; ++kc2) {
                Frag Pf;
                const int R = wb * 16 + ln;
                Pf.v = *(const bf16x8*)(Pbs + R * 64 + (((kc2 * 4 + qd) ^ (R & 7)) * 8));
                #pragma unroll
                for (int nd = 0; nd < 8; ++nd) {
                    int dcol = nd * 16 + ln;
                    int voff = dcol * 64 + (((kc2 * 4 + qd) ^ (dcol & 7)) * 8);
                    Frag Vh2;
                    Vh2.v = *(const bf16x8*)(Vhs + voff);
                    accO[nd] = __builtin_amdgcn_mfma_f32_16x16x32_bf16(Pf.v, Vh2.v, accO[nd], 0, 0, 0);
                }
            }
        }

        if (jt < jt_end) {  // convert next tile late: VALU overlaps this tile's MFMA tail
            #pragma unroll
            for (int itr = 0; itr < 4; ++itr) {
                uint32_t hp0, lp0, hp1, lp1;
                split2(kreg[itr].x, kreg[itr].y, hp0, lp0);
                split2(kreg[itr].z, kreg[itr].w, hp1, lp1);
                khi[itr] = make_uint2(hp0, hp1);
                klo[itr] = make_uint2(lp0, lp1);
            }
            #pragma unroll
            for (int uu = 0; uu < 2; ++uu) {
                Pack8 p8;
                #pragma unroll
                for (int j = 0; j < 8; ++j) p8.s[j] = bf16_rne(vraw[uu][j]);
                vcv[uu] = p8.q;
            }
        }
    }

    // ---- epilogue: reduce deferred l across the 16 lanes of each row, then O/l, stats x8 ----
    #pragma unroll
    for (int r = 0; r < 4; ++r) {
        #pragma unroll
        for (int off = 1; off < 16; off <<= 1) l_r[r] += __shfl_xor(l_r[r], off);
    }
    #pragma unroll
    for (int r = 0; r < 4; ++r) {
        const int rowg = qrow0 + qd * 4 + r;
        const float invl = 1.0f / l_r[r];
        float* op = out_o + (size_t)h * SEQ * D_DIM + (size_t)rowg * D_DIM;
        #pragma unroll
        for (int nd = 0; nd < 8; ++nd) op[nd * 16 + ln] = accO[nd][r] * invl;
        if (ln < 8) {
            size_t sb = ((size_t)h * SEQ + rowg) * 8 + ln;
            out_m[sb] = m_r[r];
            out_l[sb] = l_r[r];
        }
    }
}

extern "C" void kernel_launch(void* const* d_in, const int* in_sizes, int n_in,
                              void* d_out, int out_size, void* d_ws, size_t ws_size,
                              hipStream_t stream) {
    const float* q = (const float*)d_in[0];
    const float* k = (const float*)d_in[1];
    const float* v = (const float*)d_in[2];
    float* out = (float*)d_out;
    (void)d_ws; (void)ws_size;

    fa_fused<<<dim3(512), dim3(512), 0, stream>>>(q, k, v, out);
}

// Round 9
// 227.142 us; speedup vs baseline: 1.2145x; 1.2145x over previous
//
#include <hip/hip_runtime.h>
#include <math.h>
#include <stdint.h>

#define D_DIM 128
#define SEQ 2048
#define NHEADS 32
#define BC 64
#define SCALE 0.08838834764831843f  // 1/sqrt(128)

typedef short bf16x8 __attribute__((ext_vector_type(8)));
typedef float f32x4 __attribute__((ext_vector_type(4)));

union Frag { uint32_t u[4]; bf16x8 v; unsigned short s[8]; };
union Pack8 { unsigned short s[8]; uint4 q; };

__device__ __forceinline__ uint32_t fbits(float x) { return __builtin_bit_cast(uint32_t, x); }
__device__ __forceinline__ float bbits(uint32_t u) { return __builtin_bit_cast(float, u); }
__device__ __forceinline__ unsigned short bf16_rne(float x) {
    uint32_t u = fbits(x);
    u += 0x7FFFu + ((u >> 16) & 1u);
    return (unsigned short)(u >> 16);
}
// hi = truncate-to-bf16(x) (exact residual), lo = bf16(x - hi). even->low16, odd->high16.
__device__ __forceinline__ void split2(float a, float b, uint32_t& hp, uint32_t& lp) {
    uint32_t ua = fbits(a) & 0xFFFF0000u, ub = fbits(b) & 0xFFFF0000u;
    float la = a - bbits(ua), lb = b - bbits(ub);
    hp = (ua >> 16) | ub;
    lp = (fbits(la) >> 16) | (fbits(lb) & 0xFFFF0000u);
}

// ---------------- fused attention: conversion + FA in one kernel ----------------
// R9: scheduler-assumption-free balance + double-buffered LDS.
//  - R8 disproved the (x, x+256) co-residency model (remap regressed 152->193us).
//    New: 256 blocks, each processes q-tiles (15-xi) THEN (xi) of its head ->
//    exactly 34 KV-tile-units per block, equal for EVERY block, so CU balance holds
//    under ANY block->CU mapping. 1 block/CU.
//  - 1 block/CU frees LDS: double-buffer K/V tiles (2x48KB + Pbs 16KB = 112KB < 160KB).
//    Loop now has ONE barrier per KV-tile: compute(jt, buf[cur]) || load(jt+1);
//    convert; ds_write(jt+1 -> buf[cur^1]) [no wait: other buffer]; __syncthreads().
//    (R7 needed two barriers/tile because staging overwrote the single buffer.)
//  - Kept from R7: T14 issue-early/convert-late, exact alpha==1 skip, SCALE folded
//    into Q, deferred per-lane l, interior-tile mask skip.
// 16x16x32 bf16 MFMA; layouts: A[m=lane&15][k=quad*8+j], B[k=quad*8+j][n=lane&15],
// C/D[row=quad*4+reg][col=lane&15].
// Khs[n*128 + ((kc8^(n&7))*8)]  (n=row 0..63, kc8=k-chunk-of-8 0..15), Kls same.
// Vhs[d*64 + ((cc^(d&7))*8) + j] = bf16_rne(V[c0+cc*8+j][d]).
__global__ __launch_bounds__(512, 2) void fa_fused(
    const float* __restrict__ q, const float* __restrict__ k,
    const float* __restrict__ v, float* __restrict__ out)
{
    __shared__ __align__(16) unsigned short KhsB[2][64 * 128];   // 2 x 16KB
    __shared__ __align__(16) unsigned short KlsB[2][64 * 128];   // 2 x 16KB
    __shared__ __align__(16) unsigned short VhsB[2][128 * 64];   // 2 x 16KB
    __shared__ __align__(16) unsigned short Pbs[128 * 64];       // 16KB -> 112KB total

    const int x  = blockIdx.x;      // 256 blocks = 32 heads x 8 xi
    const int xi = x >> 5;          // 0..7
    const int h  = x & 31;

    const int t    = (int)threadIdx.x;
    const int wb   = t >> 6;
    const int lane = t & 63;
    const int ln   = lane & 15;
    const int qd   = lane >> 4;

    const float* qh = q + (size_t)h * SEQ * D_DIM;
    const float* kh = k + (size_t)h * SEQ * D_DIM;
    const float* vh = v + (size_t)h * SEQ * D_DIM;
    float* out_o = out;
    float* out_m = out + (size_t)NHEADS * SEQ * D_DIM;
    float* out_l = out_m + (size_t)NHEADS * SEQ * 8;

    // per-thread K staging coordinates (over 2048 float4 chunks of the 64x128 tile)
    const int krow0 = t >> 5;          // +16 per itr
    const int kd4   = t & 31;
    // per-thread V staging coordinates (2 units: uu selects d-half within wave's cc)
    const int vcc   = wb;
    const int vd0   = lane;            // d = uu*64 + lane

    // two balanced phases: q-tile (15-xi) then (xi); every block = 34 tile-units total
    for (int ph = 0; ph < 2; ++ph) {
        const int it = ph ? xi : (15 - xi);
        const int qrow0 = it * 128 + wb * 16;

        // Q fragments (exact hi/lo split of SCALE*q) in registers: 32 VGPRs
        Frag Qh[4], Ql[4];
        {
            const float* qp = qh + (size_t)(qrow0 + ln) * D_DIM;
            #pragma unroll
            for (int kc = 0; kc < 4; ++kc) {
                const int kb = kc * 32 + qd * 8;
                float e[8];
                *(float4*)(e)     = *(const float4*)(qp + kb);
                *(float4*)(e + 4) = *(const float4*)(qp + kb + 4);
                #pragma unroll
                for (int j = 0; j < 8; ++j) e[j] *= SCALE;   // fold score scaling into Q
                #pragma unroll
                for (int j = 0; j < 4; ++j)
                    split2(e[2 * j], e[2 * j + 1], Qh[kc].u[j], Ql[kc].u[j]);
            }
        }

        // pipeline registers: raw (in-flight) and converted (ready-to-store) K/V
        float4 kreg[4];
        float  vraw[2][8];
        uint2  khi[4], klo[4];
        uint4  vcv[2];

        // ---- prologue: tile 0 load + convert + write into buf 0 ----
        #pragma unroll
        for (int itr = 0; itr < 4; ++itr)
            kreg[itr] = *(const float4*)(kh + (size_t)(itr * 16 + krow0) * D_DIM + kd4 * 4);
        #pragma unroll
        for (int uu = 0; uu < 2; ++uu) {
            const int d = uu * 64 + vd0;
            #pragma unroll
            for (int j = 0; j < 8; ++j)
                vraw[uu][j] = vh[(size_t)(vcc * 8 + j) * D_DIM + d];
        }
        #pragma unroll
        for (int itr = 0; itr < 4; ++itr) {
            uint32_t hp0, lp0, hp1, lp1;
            split2(kreg[itr].x, kreg[itr].y, hp0, lp0);
            split2(kreg[itr].z, kreg[itr].w, hp1, lp1);
            khi[itr] = make_uint2(hp0, hp1);
            klo[itr] = make_uint2(lp0, lp1);
        }
        #pragma unroll
        for (int uu = 0; uu < 2; ++uu) {
            Pack8 p8;
            #pragma unroll
            for (int j = 0; j < 8; ++j) p8.s[j] = bf16_rne(vraw[uu][j]);
            vcv[uu] = p8.q;
        }
        {
            unsigned short* Kh0 = KhsB[0];
            unsigned short* Kl0 = KlsB[0];
            unsigned short* Vh0 = VhsB[0];
            #pragma unroll
            for (int itr = 0; itr < 4; ++itr) {
                const int row = itr * 16 + krow0;
                const int off = row * 128 + (((kd4 >> 1) ^ (row & 7)) * 8) + (kd4 & 1) * 4;
                *(uint2*)(Kh0 + off) = khi[itr];
                *(uint2*)(Kl0 + off) = klo[itr];
            }
            #pragma unroll
            for (int uu = 0; uu < 2; ++uu) {
                const int d = uu * 64 + vd0;
                *(uint4*)(Vh0 + d * 64 + ((vcc ^ (d & 7)) * 8)) = vcv[uu];
            }
        }
        __syncthreads();  // buf0 visible (also guards Pbs/LDS reuse from previous phase)

        f32x4 accO[8];
        float m_r[4], l_r[4];   // l_r is a PER-LANE partial (alpha is row-uniform, so exact)
        #pragma unroll
        for (int nd = 0; nd < 8; ++nd) accO[nd] = (f32x4){0.f, 0.f, 0.f, 0.f};
        #pragma unroll
        for (int r = 0; r < 4; ++r) { m_r[r] = -INFINITY; l_r[r] = 0.f; }

        const int jt_end = 2 * it + 1;
        for (int jt = 0; jt <= jt_end; ++jt) {
            const int c0  = jt * BC;
            const int cur = jt & 1;

            if (jt < jt_end) {  // issue next tile's raw loads (latency hides under compute)
                const int c0n = c0 + BC;
                const float* kp2 = kh + (size_t)c0n * D_DIM;
                #pragma unroll
                for (int itr = 0; itr < 4; ++itr)
                    kreg[itr] = *(const float4*)(kp2 + (size_t)(itr * 16 + krow0) * D_DIM + kd4 * 4);
                #pragma unroll
                for (int uu = 0; uu < 2; ++uu) {
                    const int d = uu * 64 + vd0;
                    #pragma unroll
                    for (int j = 0; j < 8; ++j)
                        vraw[uu][j] = vh[(size_t)(c0n + vcc * 8 + j) * D_DIM + d];
                }
            }

            if (c0 <= qrow0 + 15) {  // wave-uniform causal skip
                const unsigned short* Khs = KhsB[cur];
                const unsigned short* Kls = KlsB[cur];
                const unsigned short* Vhs = VhsB[cur];
                // ---- S = (scaled Q) K^T (split-3: hh + hl + lh), 48 MFMAs ----
                f32x4 accS[4];
                #pragma unroll
                for (int nt = 0; nt < 4; ++nt) accS[nt] = (f32x4){0.f, 0.f, 0.f, 0.f};
                #pragma unroll
                for (int kc = 0; kc < 4; ++kc) {
                    #pragma unroll
                    for (int nt = 0; nt < 4; ++nt) {
                        int n = nt * 16 + ln;
                        int off = n * 128 + (((kc * 4 + qd) ^ (n & 7)) * 8);
                        Frag Bh, Bl;
                        Bh.v = *(const bf16x8*)(Khs + off);
                        Bl.v = *(const bf16x8*)(Kls + off);
                        f32x4 c = accS[nt];
                        c = __builtin_amdgcn_mfma_f32_16x16x32_bf16(Qh[kc].v, Bh.v, c, 0, 0, 0);
                        c = __builtin_amdgcn_mfma_f32_16x16x32_bf16(Qh[kc].v, Bl.v, c, 0, 0, 0);
                        c = __builtin_amdgcn_mfma_f32_16x16x32_bf16(Ql[kc].v, Bh.v, c, 0, 0, 0);
                        accS[nt] = c;
                    }
                }
                // ---- online softmax ----
                const bool needMask = (c0 + 63 > qrow0);  // interior tiles need no causal mask
                float mxr[4];
                #pragma unroll
                for (int r = 0; r < 4; ++r) {
                    const int rowg = qrow0 + qd * 4 + r;
                    float mx = -INFINITY;
                    #pragma unroll
                    for (int nt = 0; nt < 4; ++nt) {
                        float s = accS[nt][r];
                        if (needMask && (c0 + nt * 16 + ln > rowg)) s = -INFINITY;  // causal
                        accS[nt][r] = s;
                        mx = fmaxf(mx, s);
                    }
                    mxr[r] = mx;
                }
                #pragma unroll
                for (int r = 0; r < 4; ++r) {
                    #pragma unroll
                    for (int off = 1; off < 16; off <<= 1) mxr[r] = fmaxf(mxr[r], __shfl_xor(mxr[r], off));
                }
                // exact alpha==1 skip: if no row's max grew, rescale is multiply-by-1.0
                const bool grow = (mxr[0] > m_r[0]) | (mxr[1] > m_r[1]) |
                                  (mxr[2] > m_r[2]) | (mxr[3] > m_r[3]);
                if (__any(grow)) {
                    #pragma unroll
                    for (int r = 0; r < 4; ++r) {
                        const float mnew = fmaxf(m_r[r], mxr[r]);
                        const float alpha = __expf(m_r[r] - mnew);  // first live tile: exp(-inf)=0
                        m_r[r] = mnew;
                        l_r[r] *= alpha;
                        #pragma unroll
                        for (int nd = 0; nd < 8; ++nd) accO[nd][r] *= alpha;
                    }
                }
                // pass 2: exponentials, per-lane l partial, P -> LDS
                #pragma unroll
                for (int r = 0; r < 4; ++r) {
                    float p[4];
                    #pragma unroll
                    for (int nt = 0; nt < 4; ++nt) p[nt] = __expf(accS[nt][r] - m_r[r]);
                    l_r[r] += (p[0] + p[1]) + (p[2] + p[3]);    // per-lane partial
                    const int R = wb * 16 + qd * 4 + r;  // intra-wave P region
                    #pragma unroll
                    for (int nt = 0; nt < 4; ++nt) {
                        int c = nt * 16 + ln;
                        Pbs[R * 64 + (((c >> 3) ^ (R & 7)) * 8) + (c & 7)] = bf16_rne(p[nt]);
                    }
                }
                // ---- O += P V_hi, 16 MFMAs ----
                #pragma unroll
                for (int kc2 = 0; kc2 < 2; ++kc2) {
                    Frag Pf;
                    const int R = wb * 16 + ln;
                    Pf.v = *(const bf16x8*)(Pbs + R * 64 + (((kc2 * 4 + qd) ^ (R & 7)) * 8));
                    #pragma unroll
                    for (int nd = 0; nd < 8; ++nd) {
                        int dcol = nd * 16 + ln;
                        int voff = dcol * 64 + (((kc2 * 4 + qd) ^ (dcol & 7)) * 8);
                        Frag Vh2;
                        Vh2.v = *(const bf16x8*)(Vhs + voff);
                        accO[nd] = __builtin_amdgcn_mfma_f32_16x16x32_bf16(Pf.v, Vh2.v, accO[nd], 0, 0, 0);
                    }
                }
            }

            if (jt < jt_end) {  // convert + write NEXT tile into the OTHER buffer (no wait needed)
                #pragma unroll
                for (int itr = 0; itr < 4; ++itr) {
                    uint32_t hp0, lp0, hp1, lp1;
                    split2(kreg[itr].x, kreg[itr].y, hp0, lp0);
                    split2(kreg[itr].z, kreg[itr].w, hp1, lp1);
                    khi[itr] = make_uint2(hp0, hp1);
                    klo[itr] = make_uint2(lp0, lp1);
                }
                #pragma unroll
                for (int uu = 0; uu < 2; ++uu) {
                    Pack8 p8;
                    #pragma unroll
                    for (int j = 0; j < 8; ++j) p8.s[j] = bf16_rne(vraw[uu][j]);
                    vcv[uu] = p8.q;
                }
                unsigned short* Khn = KhsB[cur ^ 1];
                unsigned short* Kln = KlsB[cur ^ 1];
                unsigned short* Vhn = VhsB[cur ^ 1];
                #pragma unroll
                for (int itr = 0; itr < 4; ++itr) {
                    const int row = itr * 16 + krow0;
                    const int off = row * 128 + (((kd4 >> 1) ^ (row & 7)) * 8) + (kd4 & 1) * 4;
                    *(uint2*)(Khn + off) = khi[itr];
                    *(uint2*)(Kln + off) = klo[itr];
                }
                #pragma unroll
                for (int uu = 0; uu < 2; ++uu) {
                    const int d = uu * 64 + vd0;
                    *(uint4*)(Vhn + d * 64 + ((vcc ^ (d & 7)) * 8)) = vcv[uu];
                }
            }

            __syncthreads();  // single barrier per tile: next buf visible, cur buf free
        }

        // ---- epilogue: reduce deferred l across the 16 lanes of each row, then O/l, stats x8 ----
        #pragma unroll
        for (int r = 0; r < 4; ++r) {
            #pragma unroll
            for (int off = 1; off < 16; off <<= 1) l_r[r] += __shfl_xor(l_r[r], off);
        }
        #pragma unroll
        for (int r = 0; r < 4; ++r) {
            const int rowg = qrow0 + qd * 4 + r;
            const float invl = 1.0f / l_r[r];
            float* op = out_o + (size_t)h * SEQ * D_DIM + (size_t)rowg * D_DIM;
            #pragma unroll
            for (int nd = 0; nd < 8; ++nd) op[nd * 16 + ln] = accO[nd][r] * invl;
            if (ln < 8) {
                size_t sb = ((size_t)h * SEQ + rowg) * 8 + ln;
                out_m[sb] = m_r[r];
                out_l[sb] = l_r[r];
            }
        }
    }
}

extern "C" void kernel_launch(void* const* d_in, const int* in_sizes, int n_in,
                              void* d_out, int out_size, void* d_ws, size_t ws_size,
                              hipStream_t stream) {
    const float* q = (const float*)d_in[0];
    const float* k = (const float*)d_in[1];
    const float* v = (const float*)d_in[2];
    float* out = (float*)d_out;
    (void)d_ws; (void)ws_size;

    fa_fused<<<dim3(256), dim3(512), 0, stream>>>(q, k, v, out);
}